// Round 7
// baseline (283.818 us; speedup 1.0000x reference)
//
#include <hip/hip_runtime.h>
#include <hip/hip_bf16.h>

#define NN 10000
#define KK 32
#define DDIRIN 10
#define DDIR 64
#define DD 128          // D_DIST == D_DIST_IN == D_ATOM == 128

typedef short bf16x8 __attribute__((ext_vector_type(8)));
typedef float f32x4  __attribute__((ext_vector_type(4)));
typedef float f32x2  __attribute__((ext_vector_type(2)));

__device__ __forceinline__ float silu_f(float x) { return x / (1.0f + __expf(-x)); }

// packed f32x2 -> bf16x2 (RNE) -> raw shorts
__device__ __forceinline__ ushort2 pk_bf16(float a, float b) {
    __hip_bfloat162 h = __float22bfloat162_rn(float2{a, b});
    union { __hip_bfloat162 h; ushort2 u; } v; v.h = h;
    return v.u;
}

// ---- Kernel 1: dir MLPs (10->64 x2) into ws, PLUS dWb bf16 pack (32 blocks) ----
// Runs FIRST: gemm consumes dWb.
__global__ __launch_bounds__(256) void dirprep_kernel(
    const float* __restrict__ nde,
    const float* __restrict__ sW, const float* __restrict__ sb,
    const float* __restrict__ tW, const float* __restrict__ tb,
    const float* __restrict__ dW,
    float* __restrict__ sd, float* __restrict__ td, ushort* __restrict__ dWb)
{
    int b = blockIdx.x;
    if (b < 32) {
        // dWb[ncol][k] = bf16(dW[k][ncol])  (col-major bf16, 32 KB)
        int v = b * 256 + threadIdx.x;        // 0..8191
        int ncol = v >> 6;
        int k0   = (v & 63) * 2;
        ushort2 u = pk_bf16(dW[k0 * DD + ncol], dW[(k0 + 1) * DD + ncol]);
        *reinterpret_cast<ushort2*>(&dWb[ncol * DD + k0]) = u;
        return;
    }
    int gid = (b - 32) * 256 + threadIdx.x;   // 0..639999 exactly
    int n = gid >> 6, d = gid & 63;
    float a = sb[d], t = tb[d];
    const float* x = nde + n * DDIRIN;
#pragma unroll
    for (int i = 0; i < DDIRIN; ++i) {
        float xv = x[i];
        a = fmaf(xv, sW[i * DDIR + d], a);
        t = fmaf(xv, tW[i * DDIR + d], t);
    }
    sd[gid] = silu_f(a);
    td[gid] = silu_f(t);
}

// ---- Kernel 2: dims 0..128. PERSISTENT software-pipelined MFMA GEMM. ----
// 2-node tiles (64 edge rows, 32 KB f32). Grid = 768 blocks (3/CU), each block
// loops tiles with stride: cvt+ds_write tile t -> barrier -> issue loads t+G
// -> MFMA+epilogue(t) -> barrier. Prefetch is in flight during MFMA/epilogue,
// bfrag amortized over ~6.5 tiles/block. Masked rows zeroed at staging;
// epilogue corrects with sum_masked = sum_all - (32-cnt)*silu(bias).
template<bool PREB>
__global__ __launch_bounds__(256, 3) void gemm_kernel(
    const float* __restrict__ edist,   // [N,32,128]
    const int*   __restrict__ nmask,   // [N,32]
    const float* __restrict__ dW,      // [128,128]
    const float* __restrict__ db,      // [128]
    const ushort* __restrict__ dWb,    // [128,128] bf16 col-major (or null)
    float* __restrict__ out)           // [N,512]
{
    const int tid  = threadIdx.x;
    const int wid  = tid >> 6;       // wave -> output cols [32*wid, 32*wid+32)
    const int lane = tid & 63;
    const int l15  = lane & 15;
    const int quad = lane >> 4;

    __shared__ __align__(16) short s_E[64 * 128];   // 16 KB bf16, swizzled

    // ---- B fragments: loaded ONCE per persistent block ----
    bf16x8 bfrag[2][4];
    float  bias[2];
    if constexpr (PREB) {
#pragma unroll
        for (int c2 = 0; c2 < 2; ++c2) {
            int ncol = (2 * wid + c2) * 16 + l15;
            bias[c2] = db[ncol];
#pragma unroll
            for (int t = 0; t < 4; ++t)
                bfrag[c2][t] = *reinterpret_cast<const bf16x8*>(
                    &dWb[ncol * DD + t * 32 + quad * 8]);
        }
    } else {
#pragma unroll
        for (int c2 = 0; c2 < 2; ++c2) {
            int ncol = (2 * wid + c2) * 16 + l15;
            bias[c2] = db[ncol];
#pragma unroll
            for (int t = 0; t < 4; ++t) {
                bf16x8 v;
#pragma unroll
                for (int j2 = 0; j2 < 4; ++j2) {
                    int k0 = t * 32 + quad * 8 + 2 * j2;
                    ushort2 u = pk_bf16(dW[k0 * DD + ncol], dW[(k0 + 1) * DD + ncol]);
                    v[2 * j2]     = (short)u.x;
                    v[2 * j2 + 1] = (short)u.y;
                }
                bfrag[c2][t] = v;
            }
        }
    }

    const int NT     = NN / 2;        // 5000 tiles
    const int stride = gridDim.x;
    int tile = blockIdx.x;

    // ---- Prologue: issue loads for first tile ----
    f32x4 va[4], vb[4];
    int   mval;
    {
        const f32x4* E4 = reinterpret_cast<const f32x4*>(edist) + (size_t)tile * 2048;
#pragma unroll
        for (int i = 0; i < 4; ++i) {
            int f0 = 2 * tid + 512 * i;
            va[i] = E4[f0];
            vb[i] = E4[f0 + 1];
        }
        mval = nmask[tile * 64 + lane];   // lane <-> edge row of this tile
    }

    while (true) {
        const unsigned long long bits = __ballot(mval != 0);
        const float cnt0 = (float)__popcll(bits & 0xffffffffull);
        const float cnt1 = (float)__popcll(bits >> 32);
        const int   n0   = tile * 2;

        // ---- cvt f32->bf16, mask-zero, swizzled ds_write (consumes va/vb) ----
#pragma unroll
        for (int i = 0; i < 4; ++i) {
            int row = (tid >> 4) + 16 * i;
            f32x4 a = va[i], b = vb[i];
            ushort2 u0 = pk_bf16(a[0], a[1]), u1 = pk_bf16(a[2], a[3]);
            ushort2 u2 = pk_bf16(b[0], b[1]), u3 = pk_bf16(b[2], b[3]);
            bf16x8 v;
            v[0] = (short)u0.x; v[1] = (short)u0.y; v[2] = (short)u1.x; v[3] = (short)u1.y;
            v[4] = (short)u2.x; v[5] = (short)u2.y; v[6] = (short)u3.x; v[7] = (short)u3.y;
            bf16x8 z;
#pragma unroll
            for (int q = 0; q < 8; ++q) z[q] = 0;
            v = ((bits >> row) & 1ull) ? v : z;
            int kb = tid & 15;
            int sw = kb ^ (row & 7);
            *reinterpret_cast<bf16x8*>(&s_E[row * 128 + sw * 8]) = v;
        }
        __syncthreads();   // ds_writes visible; no global loads outstanding here

        // ---- Prefetch NEXT tile (in flight during MFMA + epilogue) ----
        const int  ntile = tile + stride;
        const bool more  = (ntile < NT);
        if (more) {
            const f32x4* E4n = reinterpret_cast<const f32x4*>(edist) + (size_t)ntile * 2048;
#pragma unroll
            for (int i = 0; i < 4; ++i) {
                int f0 = 2 * tid + 512 * i;
                va[i] = E4n[f0];
                vb[i] = E4n[f0 + 1];
            }
            mval = nmask[ntile * 64 + lane];
        }

        // ---- MFMA: C[64 rows x 128 cols]; wave owns 32 cols, 4 row-tiles ----
        f32x4 acc[4][2];
#pragma unroll
        for (int rt = 0; rt < 4; ++rt)
#pragma unroll
            for (int c2 = 0; c2 < 2; ++c2)
#pragma unroll
                for (int g = 0; g < 4; ++g) acc[rt][c2][g] = 0.0f;

#pragma unroll
        for (int rt = 0; rt < 4; ++rt) {
            bf16x8 af[4];
            int r = rt * 16 + l15;
#pragma unroll
            for (int t = 0; t < 4; ++t) {
                int kb = (4 * t + quad) ^ (l15 & 7);
                af[t] = *reinterpret_cast<const bf16x8*>(&s_E[r * 128 + kb * 8]);
            }
#pragma unroll
            for (int t = 0; t < 4; ++t) {
                acc[rt][0] = __builtin_amdgcn_mfma_f32_16x16x32_bf16(af[t], bfrag[0][t], acc[rt][0], 0, 0, 0);
                acc[rt][1] = __builtin_amdgcn_mfma_f32_16x16x32_bf16(af[t], bfrag[1][t], acc[rt][1], 0, 0, 0);
            }
        }

        // ---- Epilogue. D layout: col=l15, row=quad*4+g (+16*rt). ----
#pragma unroll
        for (int c2 = 0; c2 < 2; ++c2) {
            float sbv = silu_f(bias[c2]);
#pragma unroll
            for (int nd = 0; nd < 2; ++nd) {
                float p = 0.0f;
#pragma unroll
                for (int h = 0; h < 2; ++h) {
                    int rt = 2 * nd + h;
#pragma unroll
                    for (int g = 0; g < 4; ++g)
                        p += silu_f(acc[rt][c2][g] + bias[c2]);
                }
                p += __shfl_xor(p, 16);
                p += __shfl_xor(p, 32);
                if (quad == nd) {
                    float c = (nd == 0) ? cnt0 : cnt1;
                    float val = (p - (32.0f - c) * sbv) / (c + 1e-5f);
                    out[(size_t)(n0 + nd) * 512 + (2 * wid + c2) * 16 + l15] = val;
                }
            }
        }

        if (!more) break;        // uniform across block
        __syncthreads();         // protect s_E before next overwrite; drains prefetch
        tile = ntile;
    }
}

// ---- Kernel 3: dims 128..512. One wave per node; ballot-compacted neighbor list. ----
template<bool USE_WS>
__global__ __launch_bounds__(256) void seg_kernel(
    const int*   __restrict__ an,      // [N]
    const float* __restrict__ nde,     // [N,10]
    const int*   __restrict__ nl,      // [N,32]
    const int*   __restrict__ nmask,   // [N,32]
    const float* __restrict__ semb,    // [100,128]
    const float* __restrict__ temb,    // [100,128]
    const float* __restrict__ sW, const float* __restrict__ sb,
    const float* __restrict__ tW, const float* __restrict__ tb,
    const float* __restrict__ sd_ws,   // [N,64] or null
    const float* __restrict__ td_ws,   // [N,64] or null
    float* __restrict__ out)           // [N,512]
{
    const int tid  = threadIdx.x;
    const int wid  = tid >> 6;
    const int lane = tid & 63;
    const int n    = blockIdx.x * 4 + wid;

    __shared__ int s_idx[4][KK];
    __shared__ int s_aidx[4][KK];

    int j = 0; bool act = false;
    if (lane < KK) {
        j   = nl[n * KK + lane];
        act = (nmask[n * KK + lane] != 0);
    }
    unsigned long long bits = __ballot(act);
    int cnt = (int)__popcll(bits);
    if (act) {
        int rank = (int)__popcll(bits & ((1ull << lane) - 1ull));
        s_idx[wid][rank]  = j;
        s_aidx[wid][rank] = an[j];
    }
    __syncthreads();

    const float invv  = 1.0f / ((float)cnt + 1e-5f);
    const float scale = (float)cnt * invv;
    float* outn = out + (size_t)n * 512;

    // sender dir (128..192), d = lane
    {
        float s = 0.0f;
        if constexpr (USE_WS) {
#pragma unroll 4
            for (int i = 0; i < cnt; ++i)
                s += sd_ws[s_idx[wid][i] * DDIR + lane];
        } else {
            for (int i = 0; i < cnt; ++i) {
                int jj = s_idx[wid][i];
                float a = sb[lane];
#pragma unroll
                for (int q = 0; q < DDIRIN; ++q)
                    a = fmaf(nde[jj * DDIRIN + q], sW[q * DDIR + lane], a);
                s += silu_f(a);
            }
        }
        outn[128 + lane] = s * invv;
    }

    // sender atom (192..320)
    {
        float s0 = 0.0f, s1 = 0.0f;
#pragma unroll 4
        for (int i = 0; i < cnt; ++i) {
            int a = s_aidx[wid][i];
            s0 += semb[a * DD + lane];
            s1 += semb[a * DD + 64 + lane];
        }
        outn[192 + lane] = s0 * invv;
        outn[256 + lane] = s1 * invv;
    }

    // recv dir (320..384)
    {
        float tdv;
        if constexpr (USE_WS) {
            tdv = td_ws[n * DDIR + lane];
        } else {
            float a = tb[lane];
#pragma unroll
            for (int q = 0; q < DDIRIN; ++q)
                a = fmaf(nde[n * DDIRIN + q], tW[q * DDIR + lane], a);
            tdv = silu_f(a);
        }
        outn[320 + lane] = tdv * scale;
    }

    // recv atom (384..512)
    {
        int ann = an[n];
        outn[384 + lane] = temb[ann * DD + lane] * scale;
        outn[448 + lane] = temb[ann * DD + 64 + lane] * scale;
    }
}

extern "C" void kernel_launch(void* const* d_in, const int* in_sizes, int n_in,
                              void* d_out, int out_size, void* d_ws, size_t ws_size,
                              hipStream_t stream) {
    const int*   an    = (const int*)  d_in[0];
    const float* nde   = (const float*)d_in[1];
    const float* edist = (const float*)d_in[2];
    const int*   nl    = (const int*)  d_in[3];
    const int*   nmask = (const int*)  d_in[4];
    const float* semb  = (const float*)d_in[5];
    const float* temb  = (const float*)d_in[6];
    const float* sW    = (const float*)d_in[7];
    const float* sb    = (const float*)d_in[8];
    const float* tW    = (const float*)d_in[9];
    const float* tb    = (const float*)d_in[10];
    const float* dW    = (const float*)d_in[11];
    const float* db    = (const float*)d_in[12];
    float* out = (float*)d_out;

    const size_t dwb_bytes = (size_t)DD * DD * sizeof(ushort);              // 32 KB
    const size_t need = dwb_bytes + (size_t)NN * DDIR * sizeof(float) * 2;  // +5.12 MB

    const int GEMM_GRID = 768;   // 3 blocks/CU x 256 CUs

    if (ws_size >= need) {
        ushort* dWb = (ushort*)d_ws;
        float*  sd  = (float*)((char*)d_ws + dwb_bytes);
        float*  td  = sd + (size_t)NN * DDIR;
        dirprep_kernel<<<32 + NN * DDIR / 256, 256, 0, stream>>>(
            nde, sW, sb, tW, tb, dW, sd, td, dWb);
        gemm_kernel<true><<<GEMM_GRID, 256, 0, stream>>>(edist, nmask, dW, db, dWb, out);
        seg_kernel<true><<<NN / 4, 256, 0, stream>>>(
            an, nde, nl, nmask, semb, temb, sW, sb, tW, tb, sd, td, out);
    } else {
        gemm_kernel<false><<<GEMM_GRID, 256, 0, stream>>>(edist, nmask, dW, db, nullptr, out);
        seg_kernel<false><<<NN / 4, 256, 0, stream>>>(
            an, nde, nl, nmask, semb, temb, sW, sb, tW, tb, nullptr, nullptr, out);
    }
}